// Round 1
// baseline (796.947 us; speedup 1.0000x reference)
//
#include <hip/hip_runtime.h>
#include <cstdint>
#include <cstddef>

// Problem dims (fixed)
#define T_TOKENS 8192
#define H_DIM    1024
#define F_DIM    4096
#define E_NUM    8

typedef __bf16 bf16x8 __attribute__((ext_vector_type(8)));
typedef float  f32x4  __attribute__((ext_vector_type(4)));
typedef unsigned short ushort8 __attribute__((ext_vector_type(8)));

#define AS_GLOBAL(p) ((const __attribute__((address_space(1))) void*)(p))
#define AS_LDS(p)    ((__attribute__((address_space(3))) void*)(p))

__device__ inline unsigned short f2b(float f) {
  unsigned int u = __float_as_uint(f);
  unsigned int r = (u + 0x7fffu + ((u >> 16) & 1u)) >> 16;   // RNE
  return (unsigned short)r;
}
__device__ inline float b2f(unsigned short u) {
  return __uint_as_float(((unsigned int)u) << 16);
}
// gelu(v) = 0.5 v (1 + tanh(u)) = v * sigmoid(2u), u = 0.79788456(v + 0.044715 v^3)
__device__ inline float gelu_fast(float v) {
  float u2 = 1.5957691216057308f * v * (1.0f + 0.044715f * v * v);
  return v / (1.0f + __expf(-u2));
}

// ---------------------------------------------------------------------------
// Transpose + fp32->bf16 cast:  in [E][R][C] fp32  ->  out [E][C][R] bf16
// Write phase: ushort8 (16B) stores, 64B contiguous per 8 lanes (was 8B @ 32B
// stride). LDS column reads stay conflict-free via the 65-word pad.
// ---------------------------------------------------------------------------
__global__ __launch_bounds__(256) void transpose_cast_kernel(
    const float* __restrict__ in, unsigned short* __restrict__ out, int R, int C)
{
  __shared__ float tile[64][65];
  const int e  = blockIdx.z;
  const int c0 = blockIdx.x * 64;
  const int r0 = blockIdx.y * 64;
  const float* src = in + (size_t)e * R * C;
  unsigned short* dst = out + (size_t)e * R * C;
  const int tid = threadIdx.x;
  const int rl  = tid >> 4;
  const int cl4 = (tid & 15) * 4;
#pragma unroll
  for (int i = 0; i < 4; ++i) {
    float4 v = *(const float4*)(src + (size_t)(r0 + rl + i * 16) * C + c0 + cl4);
    tile[rl + i * 16][cl4 + 0] = v.x;
    tile[rl + i * 16][cl4 + 1] = v.y;
    tile[rl + i * 16][cl4 + 2] = v.z;
    tile[rl + i * 16][cl4 + 3] = v.w;
  }
  __syncthreads();
#pragma unroll
  for (int itw = 0; itw < 2; ++itw) {
    int g  = itw * 256 + tid;       // 512 items: 64 dst rows x 8 chunks
    int c  = g >> 3;                // dst row (source column)
    int rc = g & 7;                 // 8-element chunk along source rows
    ushort8 u;
#pragma unroll
    for (int k = 0; k < 8; ++k) u[k] = f2b(tile[rc * 8 + k][c]);
    *(ushort8*)(dst + (size_t)(c0 + c) * R + r0 + rc * 8) = u;
  }
}

// ---------------------------------------------------------------------------
// Zero the routing counters (d_ws is poisoned before every call).
// ---------------------------------------------------------------------------
__global__ void zero_meta_kernel(int* __restrict__ counts) {
  if (threadIdx.x < 24) counts[threadIdx.x] = 0;   // counts[8], offsets[8], cursor[8]
}

// ---------------------------------------------------------------------------
// Router: logits (fp32) -> softmax -> top-2; casts x to bf16; block-aggregated
// expert counts -> global atomics.
// ---------------------------------------------------------------------------
__global__ __launch_bounds__(256) void router_kernel(
    const float* __restrict__ x, const float* __restrict__ rw,
    unsigned short* __restrict__ xb, int* __restrict__ top_e, float* __restrict__ top_p,
    int* __restrict__ counts)
{
  __shared__ float lrw[H_DIM * 9];   // padded stride 9 to spread banks
  __shared__ int lc[E_NUM];
  const int tid = threadIdx.x;
  if (tid < E_NUM) lc[tid] = 0;
  for (int r = tid; r < H_DIM; r += 256) {
    const float* s = rw + r * 8;
    float4 a = *(const float4*)(s);
    float4 b = *(const float4*)(s + 4);
    float* d = &lrw[r * 9];
    d[0] = a.x; d[1] = a.y; d[2] = a.z; d[3] = a.w;
    d[4] = b.x; d[5] = b.y; d[6] = b.z; d[7] = b.w;
  }
  __syncthreads();
  const int lane = tid & 63, wid = tid >> 6;
  for (int i = 0; i < 8; ++i) {
    const int t = blockIdx.x * 32 + wid * 8 + i;
    float acc[8] = {0.f, 0.f, 0.f, 0.f, 0.f, 0.f, 0.f, 0.f};
    const float* xrow = x + (size_t)t * H_DIM;
    unsigned short* xbrow = xb + (size_t)t * H_DIM;
#pragma unroll
    for (int j = 0; j < 16; ++j) {
      int h = j * 64 + lane;
      float xv = xrow[h];
      xbrow[h] = f2b(xv);
      const float* rr = &lrw[h * 9];
#pragma unroll
      for (int e = 0; e < 8; ++e) acc[e] += xv * rr[e];
    }
#pragma unroll
    for (int e = 0; e < 8; ++e) {
#pragma unroll
      for (int s = 32; s > 0; s >>= 1) acc[e] += __shfl_xor(acc[e], s, 64);
    }
    if (lane == 0) {
      float mx = acc[0];
      for (int e = 1; e < 8; ++e) mx = fmaxf(mx, acc[e]);
      float p[8]; float sum = 0.f;
      for (int e = 0; e < 8; ++e) { p[e] = expf(acc[e] - mx); sum += p[e]; }
      float inv = 1.0f / sum;
      int i1 = 0; float b1 = p[0];
      for (int e = 1; e < 8; ++e) if (p[e] > b1) { b1 = p[e]; i1 = e; }
      int i2 = (i1 == 0) ? 1 : 0; float b2 = p[i2];
      for (int e = 0; e < 8; ++e) if (e != i1 && p[e] > b2) { b2 = p[e]; i2 = e; }
      top_e[2 * t]     = i1; top_p[2 * t]     = b1 * inv;
      top_e[2 * t + 1] = i2; top_p[2 * t + 1] = b2 * inv;
      atomicAdd(&lc[i1], 1);
      atomicAdd(&lc[i2], 1);
    }
  }
  __syncthreads();
  if (tid < E_NUM) atomicAdd(&counts[tid], lc[tid]);
}

// ---------------------------------------------------------------------------
// Tiny: exclusive prefix over 8 counts -> offsets; zero cursors.
// ---------------------------------------------------------------------------
__global__ void offsets_kernel(const int* __restrict__ counts,
                               int* __restrict__ offsets, int* __restrict__ cursor) {
  if (threadIdx.x == 0) {
    int o = 0;
    for (int e = 0; e < E_NUM; ++e) { offsets[e] = o; o += counts[e]; cursor[e] = 0; }
  }
}

// ---------------------------------------------------------------------------
// Dispatch: assign each (token, k) a slot in its expert's contiguous segment.
// ---------------------------------------------------------------------------
__global__ __launch_bounds__(256) void assign_kernel(
    const int* __restrict__ top_e, const float* __restrict__ top_p,
    const int* __restrict__ offsets, int* __restrict__ cursor,
    int* __restrict__ map, float* __restrict__ gate, int* __restrict__ slot_of)
{
  __shared__ int lc[E_NUM], lb[E_NUM];
  const int tid = threadIdx.x;
  const int t = blockIdx.x * 256 + tid;
  if (tid < E_NUM) lc[tid] = 0;
  __syncthreads();
  int e0 = top_e[2 * t], e1 = top_e[2 * t + 1];
  int p0 = atomicAdd(&lc[e0], 1);
  int p1 = atomicAdd(&lc[e1], 1);
  __syncthreads();
  if (tid < E_NUM) lb[tid] = atomicAdd(&cursor[tid], lc[tid]);
  __syncthreads();
  int s0 = offsets[e0] + lb[e0] + p0;
  int s1 = offsets[e1] + lb[e1] + p1;
  map[s0] = t; gate[s0] = top_p[2 * t];
  map[s1] = t; gate[s1] = top_p[2 * t + 1];
  slot_of[2 * t] = s0; slot_of[2 * t + 1] = s1;
}

// ---------------------------------------------------------------------------
// fc1 GEMM: 256x256 tile, BK=64, 512 thr = 8 waves (2Mx4N), wave-tile 128x64,
// mfma 16x16x32 bf16, acc[8][4]. LDS 128KB = 2-slot dbuf x (A 32KB + B 32KB).
// 4 phases/K-tile (ks x mih quadrants, 16 MFMA each, B-frags reused across
// mih). Counted vmcnt(8): stage of kt+2 issued at phase 3 AFTER an
// lgkmcnt(0)-drained s_barrier (all waves' reads of that slot provably done
// -> WAR-safe), so 8 loads stay in flight across every barrier; never
// vmcnt(0) mid-loop. setprio(1) wraps each MFMA cluster (T5 - pays in phased
// schedules). Chunk-XOR swizzle on stage source + fragment read (T2: 8-slot
// spread -> 2-way bank alias = free).
// Grid (e=8, m, n): linear_id % 8 == e pins each expert to one XCD.
// ---------------------------------------------------------------------------
template <int KD, int ND, bool USE_MAP, bool GELU>
__global__ __launch_bounds__(512, 2) void moe_gemm256_kernel(
    const unsigned short* __restrict__ A, const unsigned short* __restrict__ Bt,
    const int* __restrict__ map, const float* __restrict__ gate,
    const int* __restrict__ counts, const int* __restrict__ offsets,
    unsigned short* __restrict__ C)
{
  __shared__ unsigned short ls[65536];   // 128 KB: [A0|A1|B0|B1], 16384 shorts each
  const int e   = blockIdx.x;
  const int cnt = counts[e];
  const int tile_m = blockIdx.y;
  if (tile_m * 256 >= cnt) return;
  const int off    = offsets[e];
  const int tile_n = blockIdx.z;
  const int tid    = threadIdx.x;       // 0..511

  // Staging sources: chunk g = it*512+tid ; row = g>>3 (0..255); src chunk =
  // (g&7) ^ (row&7)  (inverse swizzle so linear LDS holds swizzled layout).
  const unsigned short* aSrc[4];
  const unsigned short* bSrc[4];
#pragma unroll
  for (int it = 0; it < 4; ++it) {
    int g   = it * 512 + tid;
    int row = g >> 3;
    int cs  = (g & 7) ^ (row & 7);
    int rm  = tile_m * 256 + row;
    if (rm > cnt - 1) rm = cnt - 1;               // clamp padded rows
    int arow = USE_MAP ? map[off + rm] : (off + rm);
    aSrc[it] = A + (size_t)arow * KD + cs * 8;
    int rn = tile_n * 256 + row;
    bSrc[it] = Bt + (size_t)e * ND * KD + (size_t)rn * KD + cs * 8;
  }

  const int lane = tid & 63;
  const int wid  = tid >> 6;
  const int wm = wid >> 2, wn = wid & 3;          // 2x4 wave grid, 128x64 each
  const int lr = lane & 15, kg = lane >> 4;
  const int swz = lr & 7;                         // fragment read de-swizzle

  f32x4 acc[8][4];
#pragma unroll
  for (int mi = 0; mi < 8; ++mi)
#pragma unroll
    for (int ni = 0; ni < 4; ++ni) acc[mi][ni] = (f32x4){0.f, 0.f, 0.f, 0.f};

  constexpr int NK = KD / 64;

  auto STAGE = [&](int kt, int slot) {
    const int kof = kt * 64;
#pragma unroll
    for (int it = 0; it < 4; ++it)
      __builtin_amdgcn_global_load_lds(AS_GLOBAL(aSrc[it] + kof),
          AS_LDS(ls + slot * 16384 + (it * 512 + tid) * 8), 16, 0, 0);
#pragma unroll
    for (int it = 0; it < 4; ++it)
      __builtin_amdgcn_global_load_lds(AS_GLOBAL(bSrc[it] + kof),
          AS_LDS(ls + 32768 + slot * 16384 + (it * 512 + tid) * 8), 16, 0, 0);
  };

  // prologue: kt0 -> slot0, kt1 -> slot1; wait kt0 only (kt1 stays in flight)
  STAGE(0, 0);
  STAGE(1, 1);
  asm volatile("s_waitcnt vmcnt(8)" ::: "memory");
  asm volatile("s_barrier" ::: "memory");

#pragma unroll 1
  for (int kt = 0; kt < NK; ++kt) {
    const int s = kt & 1;
    const unsigned short* pA = ls + s * 16384 + (wm * 128 + lr) * 64;
    const unsigned short* pB = ls + 32768 + s * 16384 + (wn * 64 + lr) * 64;
    bf16x8 aF[4], bF[4];

    // ---- phase 0: ks=0, mih=0 (+ B ks=0) ----
#pragma unroll
    for (int ni = 0; ni < 4; ++ni)
      bF[ni] = *(const bf16x8*)(pB + ni * 16 * 64 + ((kg) ^ swz) * 8);
#pragma unroll
    for (int j = 0; j < 4; ++j)
      aF[j] = *(const bf16x8*)(pA + j * 16 * 64 + ((kg) ^ swz) * 8);
    asm volatile("s_barrier" ::: "memory");
    __builtin_amdgcn_s_setprio(1);
#pragma unroll
    for (int j = 0; j < 4; ++j)
#pragma unroll
      for (int ni = 0; ni < 4; ++ni)
        acc[j][ni] = __builtin_amdgcn_mfma_f32_16x16x32_bf16(aF[j], bF[ni], acc[j][ni], 0, 0, 0);
    __builtin_amdgcn_s_setprio(0);

    // ---- phase 1: ks=0, mih=1 (reuse bF) ----
#pragma unroll
    for (int j = 0; j < 4; ++j)
      aF[j] = *(const bf16x8*)(pA + (4 + j) * 16 * 64 + ((kg) ^ swz) * 8);
    asm volatile("s_barrier" ::: "memory");
    __builtin_amdgcn_s_setprio(1);
#pragma unroll
    for (int j = 0; j < 4; ++j)
#pragma unroll
      for (int ni = 0; ni < 4; ++ni)
        acc[4 + j][ni] = __builtin_amdgcn_mfma_f32_16x16x32_bf16(aF[j], bF[ni], acc[4 + j][ni], 0, 0, 0);
    __builtin_amdgcn_s_setprio(0);

    // ---- phase 2: ks=1, mih=0 (+ B ks=1) ----
#pragma unroll
    for (int ni = 0; ni < 4; ++ni)
      bF[ni] = *(const bf16x8*)(pB + ni * 16 * 64 + ((4 + kg) ^ swz) * 8);
#pragma unroll
    for (int j = 0; j < 4; ++j)
      aF[j] = *(const bf16x8*)(pA + j * 16 * 64 + ((4 + kg) ^ swz) * 8);
    asm volatile("s_barrier" ::: "memory");
    __builtin_amdgcn_s_setprio(1);
#pragma unroll
    for (int j = 0; j < 4; ++j)
#pragma unroll
      for (int ni = 0; ni < 4; ++ni)
        acc[j][ni] = __builtin_amdgcn_mfma_f32_16x16x32_bf16(aF[j], bF[ni], acc[j][ni], 0, 0, 0);
    __builtin_amdgcn_s_setprio(0);

    // ---- phase 3: ks=1, mih=1; stage kt+2 after drained barrier (WAR-safe) ----
#pragma unroll
    for (int j = 0; j < 4; ++j)
      aF[j] = *(const bf16x8*)(pA + (4 + j) * 16 * 64 + ((4 + kg) ^ swz) * 8);
    asm volatile("s_waitcnt lgkmcnt(0)" ::: "memory");  // own slot-s reads done
    asm volatile("s_barrier" ::: "memory");             // ALL waves done with slot s
    if (kt + 2 < NK) STAGE(kt + 2, s);
    __builtin_amdgcn_s_setprio(1);
#pragma unroll
    for (int j = 0; j < 4; ++j)
#pragma unroll
      for (int ni = 0; ni < 4; ++ni)
        acc[4 + j][ni] = __builtin_amdgcn_mfma_f32_16x16x32_bf16(aF[j], bF[ni], acc[4 + j][ni], 0, 0, 0);
    __builtin_amdgcn_s_setprio(0);
    if (kt + 2 < NK) {
      asm volatile("s_waitcnt vmcnt(8)" ::: "memory");  // kt+1 landed; kt+2 in flight
    } else {
      asm volatile("s_waitcnt vmcnt(0)" ::: "memory");  // tail: drain
    }
    asm volatile("s_barrier" ::: "memory");             // slot s^1 visible to all
  }

  // ---- Epilogue: activation/gate -> LDS repack (2 row-half passes) ----
  __syncthreads();
#pragma unroll
  for (int h = 0; h < 2; ++h) {
    if (h) __syncthreads();                 // store pass h-1 done before overwrite
    if (wm == h) {
#pragma unroll
      for (int mi = 0; mi < 8; ++mi) {
#pragma unroll
        for (int r = 0; r < 4; ++r) {
          int Rl = mi * 16 + kg * 4 + r;    // 0..127 within the half
          float gv = 1.0f;
          if (!GELU) {
            int gm = tile_m * 256 + h * 128 + Rl;
            int gmc = gm < cnt ? gm : cnt - 1;
            gv = gate[off + gmc];
          }
#pragma unroll
          for (int ni = 0; ni < 4; ++ni) {
            int col = wn * 64 + ni * 16 + lr;
            float v = acc[mi][ni][r];
            v = GELU ? gelu_fast(v) : v * gv;
            ls[Rl * 264 + col] = f2b(v);
          }
        }
      }
    }
    __syncthreads();
#pragma unroll
    for (int it = 0; it < 8; ++it) {
      int g = it * 512 + tid;               // 128 rows x 32 chunks of 8
      int R = g >> 5, c8 = g & 31;
      int gm = tile_m * 256 + h * 128 + R;
      if (gm < cnt) {
        ushort8 v = *(const ushort8*)(ls + R * 264 + c8 * 8);
        *(ushort8*)(C + (size_t)(off + gm) * ND + tile_n * 256 + c8 * 8) = v;
      }
    }
  }
}

// ---------------------------------------------------------------------------
// fc2 GEMM (unchanged): 128x128 tile, BK=64, 4 waves of 64x64. At N=1024 a
// 256-tile grid would be ~288 blocks @1/CU -> 2 quantized rounds (worse);
// the fine 128 tiling (~1030 blocks @2/CU) packs better.
// ---------------------------------------------------------------------------
template <int KD, int ND, bool USE_MAP, bool GELU>
__global__ __launch_bounds__(256) void moe_gemm_kernel(
    const unsigned short* __restrict__ A, const unsigned short* __restrict__ Bt,
    const int* __restrict__ map, const float* __restrict__ gate,
    const int* __restrict__ counts, const int* __restrict__ offsets,
    unsigned short* __restrict__ C)
{
  __shared__ unsigned short ls[32768];           // 64 KB: [A0|A1|B0|B1] 8192 shorts each
  const int e   = blockIdx.x;
  const int cnt = counts[e];
  const int tile_m = blockIdx.y;
  if (tile_m * 128 >= cnt) return;
  const int off    = offsets[e];
  const int tile_n = blockIdx.z;
  const int tid    = threadIdx.x;

  const unsigned short* aSrc[4];
  const unsigned short* bSrc[4];
  const int cswz = ((tid & 7) ^ ((tid >> 3) & 7)) * 8;
#pragma unroll
  for (int it = 0; it < 4; ++it) {
    int r  = it * 32 + (tid >> 3);
    int rm = tile_m * 128 + r;
    if (rm > cnt - 1) rm = cnt - 1;               // clamp padded rows
    int arow = USE_MAP ? map[off + rm] : (off + rm);
    aSrc[it] = A + (size_t)arow * KD + cswz;
    int rn = tile_n * 128 + r;
    bSrc[it] = Bt + (size_t)e * ND * KD + (size_t)rn * KD + cswz;
  }

  const int lane = tid & 63;
  const int wid  = tid >> 6;
  const int wm = wid >> 1, wn = wid & 1;          // 2x2 wave grid, 64x64 each
  const int lr = lane & 15, kg = lane >> 4;
  const int swz = lr & 7;                          // fragment read de-swizzle

  f32x4 acc[4][4];
#pragma unroll
  for (int mi = 0; mi < 4; ++mi)
#pragma unroll
    for (int ni = 0; ni < 4; ++ni) acc[mi][ni] = (f32x4){0.f, 0.f, 0.f, 0.f};

  constexpr int NK = KD / 64;

#pragma unroll
  for (int it = 0; it < 4; ++it)
    __builtin_amdgcn_global_load_lds(AS_GLOBAL(aSrc[it]),
                                     AS_LDS(ls + (it * 256 + tid) * 8), 16, 0, 0);
#pragma unroll
  for (int it = 0; it < 4; ++it)
    __builtin_amdgcn_global_load_lds(AS_GLOBAL(bSrc[it]),
                                     AS_LDS(ls + 16384 + (it * 256 + tid) * 8), 16, 0, 0);

#pragma unroll 1
  for (int k = 0; k < NK; ++k) {
    const int p = k & 1;
    asm volatile("s_barrier" ::: "memory");
    if (k + 1 < NK) {
      const int q = p ^ 1;
      const int k0 = (k + 1) * 64;
#pragma unroll
      for (int it = 0; it < 4; ++it)
        __builtin_amdgcn_global_load_lds(AS_GLOBAL(aSrc[it] + k0),
                                         AS_LDS(ls + q * 8192 + (it * 256 + tid) * 8), 16, 0, 0);
#pragma unroll
      for (int it = 0; it < 4; ++it)
        __builtin_amdgcn_global_load_lds(AS_GLOBAL(bSrc[it] + k0),
                                         AS_LDS(ls + 16384 + q * 8192 + (it * 256 + tid) * 8), 16, 0, 0);
      asm volatile("s_waitcnt vmcnt(8)" ::: "memory");   // wait iter-k loads only
    } else {
      asm volatile("s_waitcnt vmcnt(0)" ::: "memory");
    }
    asm volatile("s_barrier" ::: "memory");

    const unsigned short* pA = ls + p * 8192 + (wm * 64 + lr) * 64;
    const unsigned short* pB = ls + 16384 + p * 8192 + (wn * 64 + lr) * 64;
#pragma unroll
    for (int ks = 0; ks < 2; ++ks) {
      bf16x8 aF[4], bF[4];
#pragma unroll
      for (int i = 0; i < 4; ++i)
        aF[i] = *(const bf16x8*)(pA + i * 16 * 64 + (((ks * 4 + kg) ^ swz) * 8));
#pragma unroll
      for (int i = 0; i < 4; ++i)
        bF[i] = *(const bf16x8*)(pB + i * 16 * 64 + (((ks * 4 + kg) ^ swz) * 8));
#pragma unroll
      for (int mi = 0; mi < 4; ++mi)
#pragma unroll
        for (int ni = 0; ni < 4; ++ni)
          acc[mi][ni] = __builtin_amdgcn_mfma_f32_16x16x32_bf16(aF[mi], bF[ni],
                                                                acc[mi][ni], 0, 0, 0);
    }
  }

  __syncthreads();
#pragma unroll
  for (int mi = 0; mi < 4; ++mi) {
#pragma unroll
    for (int r = 0; r < 4; ++r) {
      int Rl = wm * 64 + mi * 16 + kg * 4 + r;
      float gv = 1.0f;
      if (!GELU) {
        int gm = tile_m * 128 + Rl;
        int gmc = gm < cnt ? gm : cnt - 1;
        gv = gate[off + gmc];
      }
#pragma unroll
      for (int ni = 0; ni < 4; ++ni) {
        int col = wn * 64 + ni * 16 + lr;
        float v = acc[mi][ni][r];
        v = GELU ? gelu_fast(v) : v * gv;
        ls[Rl * 136 + col] = f2b(v);
      }
    }
  }
  __syncthreads();
#pragma unroll
  for (int it = 0; it < 8; ++it) {
    int g = it * 256 + tid;
    int R = g >> 4, c16 = g & 15;
    int gm = tile_m * 128 + R;
    if (gm < cnt) {
      ushort8 v = *(const ushort8*)(ls + R * 136 + c16 * 8);
      *(ushort8*)(C + (size_t)(off + gm) * ND + tile_n * 128 + c16 * 8) = v;
    }
  }
}

// ---------------------------------------------------------------------------
// Combine: out[t] = y[slot0(t)] + y[slot1(t)]   (gates already applied)
// ---------------------------------------------------------------------------
__global__ __launch_bounds__(256) void combine_kernel(
    const unsigned short* __restrict__ y, const int* __restrict__ slot_of,
    float* __restrict__ out)
{
  const int t  = blockIdx.x;
  const int h0 = threadIdx.x * 4;
  const int s0 = slot_of[2 * t], s1 = slot_of[2 * t + 1];
  ushort4 a = *(const ushort4*)(y + (size_t)s0 * H_DIM + h0);
  ushort4 b = *(const ushort4*)(y + (size_t)s1 * H_DIM + h0);
  float4 o;
  o.x = b2f(a.x) + b2f(b.x);
  o.y = b2f(a.y) + b2f(b.y);
  o.z = b2f(a.z) + b2f(b.z);
  o.w = b2f(a.w) + b2f(b.w);
  *(float4*)(out + (size_t)t * H_DIM + h0) = o;
}

// ---------------------------------------------------------------------------
extern "C" void kernel_launch(void* const* d_in, const int* in_sizes, int n_in,
                              void* d_out, int out_size, void* d_ws, size_t ws_size,
                              hipStream_t stream) {
  const float* x  = (const float*)d_in[0];   // [S,B,H] = [8192,1024]
  const float* rw = (const float*)d_in[1];   // [H,E]   = [1024,8]
  const float* w1 = (const float*)d_in[2];   // [E,H,F]
  const float* w2 = (const float*)d_in[3];   // [E,F,H]
  float* out = (float*)d_out;

  char* ws = (char*)d_ws;
  unsigned short* wT     = (unsigned short*)ws;                     // 64 MB (w1t, then w2t)
  unsigned short* xb     = (unsigned short*)(ws + (64ull  << 20));  // 16 MB
  unsigned short* y      = (unsigned short*)(ws + (64ull  << 20));  // 32 MB (reuses dead xb)
  unsigned short* hidden = (unsigned short*)(ws + (96ull  << 20));  // 128 MB
  char* meta = ws + (224ull << 20);
  int*   top_e   = (int*)meta;                     // 16384
  float* top_p   = (float*)(meta + (64 << 10));    // 16384
  int*   map     = (int*)(meta + (128 << 10));     // 16384
  float* gate    = (float*)(meta + (192 << 10));   // 16384
  int*   slot_of = (int*)(meta + (256 << 10));     // 16384
  int*   counts  = (int*)(meta + (320 << 10));     // 8
  int*   offsets = counts + 8;
  int*   cursor  = counts + 16;

  // 0. zero routing counters (ws is poisoned each call)
  zero_meta_kernel<<<1, 64, 0, stream>>>(counts);
  // 1. w1 [E][H][F] fp32 -> wT = w1t [E][F][H] bf16
  transpose_cast_kernel<<<dim3(F_DIM / 64, H_DIM / 64, E_NUM), 256, 0, stream>>>(w1, wT, H_DIM, F_DIM);
  // 2. router (+ x -> bf16, + per-block expert counts)
  router_kernel<<<256, 256, 0, stream>>>(x, rw, xb, top_e, top_p, counts);
  // 3. offsets from counts
  offsets_kernel<<<1, 64, 0, stream>>>(counts, offsets, cursor);
  // 4. slot assignment
  assign_kernel<<<T_TOKENS / 256, 256, 0, stream>>>(top_e, top_p, offsets, cursor, map, gate, slot_of);
  // 5. fc1: hidden = gelu(x @ w1[e]) over routed slots  (256^2 phased kernel)
  moe_gemm256_kernel<H_DIM, F_DIM, true, true>
      <<<dim3(E_NUM, 32, F_DIM / 256), 512, 0, stream>>>(xb, wT, map, nullptr, counts, offsets, hidden);
  // 6. w2 [E][F][H] fp32 -> wT = w2t [E][H][F] bf16 (wT free after fc1; stream-serial)
  transpose_cast_kernel<<<dim3(H_DIM / 64, F_DIM / 64, E_NUM), 256, 0, stream>>>(w2, wT, F_DIM, H_DIM);
  // 7. fc2: y = gate * (hidden @ w2[e])  (128^2: packs better at N=1024)
  moe_gemm_kernel<F_DIM, H_DIM, false, false>
      <<<dim3(E_NUM, 64, H_DIM / 128), 256, 0, stream>>>(hidden, wT, nullptr, gate, counts, offsets, y);
  // 8. combine two slots per token
  combine_kernel<<<T_TOKENS, 256, 0, stream>>>(y, slot_of, out);
}

// Round 2
// 765.093 us; speedup vs baseline: 1.0416x; 1.0416x over previous
//
#include <hip/hip_runtime.h>
#include <cstdint>
#include <cstddef>

// Problem dims (fixed)
#define T_TOKENS 8192
#define H_DIM    1024
#define F_DIM    4096
#define E_NUM    8

typedef __bf16 bf16x8 __attribute__((ext_vector_type(8)));
typedef float  f32x4  __attribute__((ext_vector_type(4)));
typedef unsigned short ushort8 __attribute__((ext_vector_type(8)));

#define AS_GLOBAL(p) ((const __attribute__((address_space(1))) void*)(p))
#define AS_LDS(p)    ((__attribute__((address_space(3))) void*)(p))

__device__ inline unsigned short f2b(float f) {
  unsigned int u = __float_as_uint(f);
  unsigned int r = (u + 0x7fffu + ((u >> 16) & 1u)) >> 16;   // RNE
  return (unsigned short)r;
}
__device__ inline float b2f(unsigned short u) {
  return __uint_as_float(((unsigned int)u) << 16);
}
// gelu(v) = 0.5 v (1 + tanh(u)) = v * sigmoid(2u), u = 0.79788456(v + 0.044715 v^3)
__device__ inline float gelu_fast(float v) {
  float u2 = 1.5957691216057308f * v * (1.0f + 0.044715f * v * v);
  return v / (1.0f + __expf(-u2));
}

// ---------------------------------------------------------------------------
// Transpose + fp32->bf16 cast:  in [E][R][C] fp32  ->  out [E][C][R] bf16
// ushort8 (16B) stores, 64B contiguous per 8 lanes. Also zeroes the 24-word
// routing meta block (counts/offsets/cursor) when zc != nullptr (folds the
// old zero_meta launch into this kernel; runs before router, stream-ordered).
// ---------------------------------------------------------------------------
__global__ __launch_bounds__(256) void transpose_cast_kernel(
    const float* __restrict__ in, unsigned short* __restrict__ out, int R, int C,
    int* __restrict__ zc)
{
  __shared__ float tile[64][65];
  const int tid = threadIdx.x;
  if (zc && blockIdx.x == 0 && blockIdx.y == 0 && blockIdx.z == 0 && tid < 24)
    zc[tid] = 0;
  const int e  = blockIdx.z;
  const int c0 = blockIdx.x * 64;
  const int r0 = blockIdx.y * 64;
  const float* src = in + (size_t)e * R * C;
  unsigned short* dst = out + (size_t)e * R * C;
  const int rl  = tid >> 4;
  const int cl4 = (tid & 15) * 4;
#pragma unroll
  for (int i = 0; i < 4; ++i) {
    float4 v = *(const float4*)(src + (size_t)(r0 + rl + i * 16) * C + c0 + cl4);
    tile[rl + i * 16][cl4 + 0] = v.x;
    tile[rl + i * 16][cl4 + 1] = v.y;
    tile[rl + i * 16][cl4 + 2] = v.z;
    tile[rl + i * 16][cl4 + 3] = v.w;
  }
  __syncthreads();
#pragma unroll
  for (int itw = 0; itw < 2; ++itw) {
    int g  = itw * 256 + tid;       // 512 items: 64 dst rows x 8 chunks
    int c  = g >> 3;                // dst row (source column)
    int rc = g & 7;                 // 8-element chunk along source rows
    ushort8 u;
#pragma unroll
    for (int k = 0; k < 8; ++k) u[k] = f2b(tile[rc * 8 + k][c]);
    *(ushort8*)(dst + (size_t)(c0 + c) * R + r0 + rc * 8) = u;
  }
}

// ---------------------------------------------------------------------------
// Router: logits (fp32) -> softmax -> top-2; casts x to bf16; block-aggregated
// expert counts -> global atomics. Also zeroes `out` (fc2 accumulates into it
// with fp32 atomics; zero + two commutative adds is bit-deterministic).
// ---------------------------------------------------------------------------
__global__ __launch_bounds__(256) void router_kernel(
    const float* __restrict__ x, const float* __restrict__ rw,
    unsigned short* __restrict__ xb, int* __restrict__ top_e, float* __restrict__ top_p,
    int* __restrict__ counts, float* __restrict__ out_zero)
{
  __shared__ float lrw[H_DIM * 9];   // padded stride 9 to spread banks
  __shared__ int lc[E_NUM];
  const int tid = threadIdx.x;
  // zero out[] : 8M floats = 2M float4, 65536 threads -> 32 float4 each
  {
    float4 z = {0.f, 0.f, 0.f, 0.f};
    float4* o4 = (float4*)out_zero;
    int base = blockIdx.x * 256 + tid;
#pragma unroll
    for (int i = 0; i < 32; ++i) o4[base + i * 65536] = z;
  }
  if (tid < E_NUM) lc[tid] = 0;
  for (int r = tid; r < H_DIM; r += 256) {
    const float* s = rw + r * 8;
    float4 a = *(const float4*)(s);
    float4 b = *(const float4*)(s + 4);
    float* d = &lrw[r * 9];
    d[0] = a.x; d[1] = a.y; d[2] = a.z; d[3] = a.w;
    d[4] = b.x; d[5] = b.y; d[6] = b.z; d[7] = b.w;
  }
  __syncthreads();
  const int lane = tid & 63, wid = tid >> 6;
  for (int i = 0; i < 8; ++i) {
    const int t = blockIdx.x * 32 + wid * 8 + i;
    float acc[8] = {0.f, 0.f, 0.f, 0.f, 0.f, 0.f, 0.f, 0.f};
    const float* xrow = x + (size_t)t * H_DIM;
    unsigned short* xbrow = xb + (size_t)t * H_DIM;
#pragma unroll
    for (int j = 0; j < 16; ++j) {
      int h = j * 64 + lane;
      float xv = xrow[h];
      xbrow[h] = f2b(xv);
      const float* rr = &lrw[h * 9];
#pragma unroll
      for (int e = 0; e < 8; ++e) acc[e] += xv * rr[e];
    }
#pragma unroll
    for (int e = 0; e < 8; ++e) {
#pragma unroll
      for (int s = 32; s > 0; s >>= 1) acc[e] += __shfl_xor(acc[e], s, 64);
    }
    if (lane == 0) {
      float mx = acc[0];
      for (int e = 1; e < 8; ++e) mx = fmaxf(mx, acc[e]);
      float p[8]; float sum = 0.f;
      for (int e = 0; e < 8; ++e) { p[e] = expf(acc[e] - mx); sum += p[e]; }
      float inv = 1.0f / sum;
      int i1 = 0; float b1 = p[0];
      for (int e = 1; e < 8; ++e) if (p[e] > b1) { b1 = p[e]; i1 = e; }
      int i2 = (i1 == 0) ? 1 : 0; float b2 = p[i2];
      for (int e = 0; e < 8; ++e) if (e != i1 && p[e] > b2) { b2 = p[e]; i2 = e; }
      top_e[2 * t]     = i1; top_p[2 * t]     = b1 * inv;
      top_e[2 * t + 1] = i2; top_p[2 * t + 1] = b2 * inv;
      atomicAdd(&lc[i1], 1);
      atomicAdd(&lc[i2], 1);
    }
  }
  __syncthreads();
  if (tid < E_NUM) atomicAdd(&counts[tid], lc[tid]);
}

// ---------------------------------------------------------------------------
// Dispatch: assign each (token, k) a slot in its expert's contiguous segment.
// Offsets are computed per-block from counts (folds the old offsets_kernel);
// block 0 publishes offsets[] for the GEMMs (stream-ordered before them).
// ---------------------------------------------------------------------------
__global__ __launch_bounds__(256) void assign_kernel(
    const int* __restrict__ top_e, const float* __restrict__ top_p,
    const int* __restrict__ counts, int* __restrict__ cursor,
    int* __restrict__ map, float* __restrict__ gate, int* __restrict__ offsets)
{
  __shared__ int lc[E_NUM], lb[E_NUM], loff[E_NUM];
  const int tid = threadIdx.x;
  const int t = blockIdx.x * 256 + tid;
  if (tid < E_NUM) lc[tid] = 0;
  if (tid == 0) {
    int o = 0;
    for (int e = 0; e < E_NUM; ++e) { loff[e] = o; o += counts[e]; }
  }
  __syncthreads();
  int e0 = top_e[2 * t], e1 = top_e[2 * t + 1];
  int p0 = atomicAdd(&lc[e0], 1);
  int p1 = atomicAdd(&lc[e1], 1);
  __syncthreads();
  if (tid < E_NUM) lb[tid] = atomicAdd(&cursor[tid], lc[tid]);
  __syncthreads();
  int s0 = loff[e0] + lb[e0] + p0;
  int s1 = loff[e1] + lb[e1] + p1;
  map[s0] = t; gate[s0] = top_p[2 * t];
  map[s1] = t; gate[s1] = top_p[2 * t + 1];
  if (blockIdx.x == 0 && tid < E_NUM) offsets[tid] = loff[tid];
}

// ---------------------------------------------------------------------------
// Grouped GEMM: 128x128 tile, BK=64, 4 waves of 64x64, mfma 16x16x32 bf16.
// (Proven round-0 structure: double-buffered LDS, counted vmcnt(8), raw
// s_barrier, chunk-XOR swizzle.)
// GELU path (fc1): gelu -> LDS repack -> coalesced bf16 stores to C.
// ATOMIC_OUT path (fc2): gated fp32 atomicAdd straight into out[token]
// (fuses the old combine kernel; drops the 64MB y round-trip; exact & 
// deterministic: out starts at 0, each element gets exactly 2 commutative adds).
// ---------------------------------------------------------------------------
template <int KD, int ND, bool USE_MAP, bool GELU, bool ATOMIC_OUT>
__global__ __launch_bounds__(256) void moe_gemm_kernel(
    const unsigned short* __restrict__ A, const unsigned short* __restrict__ Bt,
    const int* __restrict__ map, const float* __restrict__ gate,
    const int* __restrict__ counts, const int* __restrict__ offsets,
    unsigned short* __restrict__ C, float* __restrict__ out)
{
  __shared__ unsigned short ls[32768];           // 64 KB: [A0|A1|B0|B1] 8192 shorts each
  const int e   = blockIdx.x;
  const int cnt = counts[e];
  const int tile_m = blockIdx.y;
  if (tile_m * 128 >= cnt) return;
  const int off    = offsets[e];
  const int tile_n = blockIdx.z;
  const int tid    = threadIdx.x;

  // Staging: chunk = it*256+tid ; row = chunk>>3 ; global chunk = (tid&7)^(row&7)
  const unsigned short* aSrc[4];
  const unsigned short* bSrc[4];
  const int cswz = ((tid & 7) ^ ((tid >> 3) & 7)) * 8;
#pragma unroll
  for (int it = 0; it < 4; ++it) {
    int r  = it * 32 + (tid >> 3);
    int rm = tile_m * 128 + r;
    if (rm > cnt - 1) rm = cnt - 1;               // clamp padded rows
    int arow = USE_MAP ? map[off + rm] : (off + rm);
    aSrc[it] = A + (size_t)arow * KD + cswz;
    int rn = tile_n * 128 + r;
    bSrc[it] = Bt + (size_t)e * ND * KD + (size_t)rn * KD + cswz;
  }

  const int lane = tid & 63;
  const int wid  = tid >> 6;
  const int wm = wid >> 1, wn = wid & 1;          // 2x2 wave grid, 64x64 each
  const int lr = lane & 15, kg = lane >> 4;
  const int swz = lr & 7;                          // fragment read de-swizzle

  f32x4 acc[4][4];
#pragma unroll
  for (int mi = 0; mi < 4; ++mi)
#pragma unroll
    for (int ni = 0; ni < 4; ++ni) acc[mi][ni] = (f32x4){0.f, 0.f, 0.f, 0.f};

  constexpr int NK = KD / 64;

  // prologue: issue iter-0 loads into buffer 0
#pragma unroll
  for (int it = 0; it < 4; ++it)
    __builtin_amdgcn_global_load_lds(AS_GLOBAL(aSrc[it]),
                                     AS_LDS(ls + (it * 256 + tid) * 8), 16, 0, 0);
#pragma unroll
  for (int it = 0; it < 4; ++it)
    __builtin_amdgcn_global_load_lds(AS_GLOBAL(bSrc[it]),
                                     AS_LDS(ls + 16384 + (it * 256 + tid) * 8), 16, 0, 0);

#pragma unroll 1
  for (int k = 0; k < NK; ++k) {
    const int p = k & 1;
    // barrier 1: everyone finished reading buffer p^1 (iter k-1 compute)
    asm volatile("s_barrier" ::: "memory");
    if (k + 1 < NK) {
      const int q = p ^ 1;
      const int k0 = (k + 1) * 64;
#pragma unroll
      for (int it = 0; it < 4; ++it)
        __builtin_amdgcn_global_load_lds(AS_GLOBAL(aSrc[it] + k0),
                                         AS_LDS(ls + q * 8192 + (it * 256 + tid) * 8), 16, 0, 0);
#pragma unroll
      for (int it = 0; it < 4; ++it)
        __builtin_amdgcn_global_load_lds(AS_GLOBAL(bSrc[it] + k0),
                                         AS_LDS(ls + 16384 + q * 8192 + (it * 256 + tid) * 8), 16, 0, 0);
      asm volatile("s_waitcnt vmcnt(8)" ::: "memory");   // wait iter-k loads only
    } else {
      asm volatile("s_waitcnt vmcnt(0)" ::: "memory");
    }
    // barrier 2: all waves' buffer-p loads complete
    asm volatile("s_barrier" ::: "memory");

    const unsigned short* pA = ls + p * 8192 + (wm * 64 + lr) * 64;
    const unsigned short* pB = ls + 16384 + p * 8192 + (wn * 64 + lr) * 64;
#pragma unroll
    for (int ks = 0; ks < 2; ++ks) {
      bf16x8 aF[4], bF[4];
#pragma unroll
      for (int i = 0; i < 4; ++i)
        aF[i] = *(const bf16x8*)(pA + i * 16 * 64 + (((ks * 4 + kg) ^ swz) * 8));
#pragma unroll
      for (int i = 0; i < 4; ++i)
        bF[i] = *(const bf16x8*)(pB + i * 16 * 64 + (((ks * 4 + kg) ^ swz) * 8));
#pragma unroll
      for (int mi = 0; mi < 4; ++mi)
#pragma unroll
        for (int ni = 0; ni < 4; ++ni)
          acc[mi][ni] = __builtin_amdgcn_mfma_f32_16x16x32_bf16(aF[mi], bF[ni],
                                                                acc[mi][ni], 0, 0, 0);
    }
  }

  if (ATOMIC_OUT) {
    // ---- fc2 epilogue: gated fp32 atomic accumulate into out[token] ----
#pragma unroll
    for (int mi = 0; mi < 4; ++mi) {
#pragma unroll
      for (int r = 0; r < 4; ++r) {
        int Rl = wm * 64 + mi * 16 + kg * 4 + r;
        int gm = tile_m * 128 + Rl;
        if (gm < cnt) {
          int   t  = map[off + gm];
          float gv = gate[off + gm];
          float* orow = out + (size_t)t * ND + tile_n * 128 + wn * 64 + lr;
#pragma unroll
          for (int ni = 0; ni < 4; ++ni)
            __hip_atomic_fetch_add(orow + ni * 16, acc[mi][ni][r] * gv,
                                   __ATOMIC_RELAXED, __HIP_MEMORY_SCOPE_AGENT);
        }
      }
    }
  } else {
    // ---- fc1 epilogue: gelu -> LDS repack -> coalesced 16B bf16 stores ----
    __syncthreads();
#pragma unroll
    for (int mi = 0; mi < 4; ++mi) {
#pragma unroll
      for (int r = 0; r < 4; ++r) {
        int Rl = wm * 64 + mi * 16 + kg * 4 + r;
#pragma unroll
        for (int ni = 0; ni < 4; ++ni) {
          int col = wn * 64 + ni * 16 + lr;
          float v = acc[mi][ni][r];
          v = GELU ? gelu_fast(v) : v;
          ls[Rl * 136 + col] = f2b(v);
        }
      }
    }
    __syncthreads();
#pragma unroll
    for (int it = 0; it < 8; ++it) {
      int g = it * 256 + tid;
      int R = g >> 4, c16 = g & 15;
      int gm = tile_m * 128 + R;
      if (gm < cnt) {
        ushort8 v = *(const ushort8*)(ls + R * 136 + c16 * 8);
        *(ushort8*)(C + (size_t)(off + gm) * ND + tile_n * 128 + c16 * 8) = v;
      }
    }
  }
}

// ---------------------------------------------------------------------------
extern "C" void kernel_launch(void* const* d_in, const int* in_sizes, int n_in,
                              void* d_out, int out_size, void* d_ws, size_t ws_size,
                              hipStream_t stream) {
  const float* x  = (const float*)d_in[0];   // [S,B,H] = [8192,1024]
  const float* rw = (const float*)d_in[1];   // [H,E]   = [1024,8]
  const float* w1 = (const float*)d_in[2];   // [E,H,F]
  const float* w2 = (const float*)d_in[3];   // [E,F,H]
  float* out = (float*)d_out;

  char* ws = (char*)d_ws;
  unsigned short* wT     = (unsigned short*)ws;                     // 64 MB (w1t, then w2t)
  unsigned short* xb     = (unsigned short*)(ws + (64ull  << 20));  // 16 MB
  unsigned short* hidden = (unsigned short*)(ws + (96ull  << 20));  // 128 MB
  char* meta = ws + (224ull << 20);
  int*   top_e   = (int*)meta;                     // 16384
  float* top_p   = (float*)(meta + (64 << 10));    // 16384
  int*   map     = (int*)(meta + (128 << 10));     // 16384
  float* gate    = (float*)(meta + (192 << 10));   // 16384
  int*   counts  = (int*)(meta + (320 << 10));     // 8
  int*   offsets = counts + 8;
  int*   cursor  = counts + 16;

  // 1. w1 [E][H][F] fp32 -> wT = w1t [E][F][H] bf16  (+ zero 24 meta words)
  transpose_cast_kernel<<<dim3(F_DIM / 64, H_DIM / 64, E_NUM), 256, 0, stream>>>(
      w1, wT, H_DIM, F_DIM, counts);
  // 2. router (+ x -> bf16, + per-block expert counts, + zero out[])
  router_kernel<<<256, 256, 0, stream>>>(x, rw, xb, top_e, top_p, counts, out);
  // 3. slot assignment (+ per-block offsets from counts; block 0 publishes)
  assign_kernel<<<T_TOKENS / 256, 256, 0, stream>>>(top_e, top_p, counts, cursor,
                                                    map, gate, offsets);
  // 4. fc1: hidden = gelu(x @ w1[e]) over routed slots
  moe_gemm_kernel<H_DIM, F_DIM, true, true, false>
      <<<dim3(E_NUM, 64, F_DIM / 128), 256, 0, stream>>>(xb, wT, map, gate,
                                                         counts, offsets, hidden, nullptr);
  // 5. w2 [E][F][H] fp32 -> wT = w2t [E][H][F] bf16 (wT free after fc1)
  transpose_cast_kernel<<<dim3(H_DIM / 64, F_DIM / 64, E_NUM), 256, 0, stream>>>(
      w2, wT, F_DIM, H_DIM, nullptr);
  // 6. fc2: out[t] += gate * (hidden @ w2[e])  (fused combine via fp32 atomics)
  moe_gemm_kernel<F_DIM, H_DIM, false, false, true>
      <<<dim3(E_NUM, 64, H_DIM / 128), 256, 0, stream>>>(hidden, wT, map, gate,
                                                         counts, offsets, nullptr, out);
}